// Round 1
// baseline (475.361 us; speedup 1.0000x reference)
//
#include <hip/hip_runtime.h>

#define B_   4
#define C_   256
#define C2_  128
#define HIN  128
#define HO   63
#define NSEQ 3969          // 63*63
#define NPAD 4032          // 63*64
#define D_   128
#define TOT  (B_*C_*NSEQ)  // 4064256

typedef _Float16 f16x8 __attribute__((ext_vector_type(8)));
typedef float    f32x4 __attribute__((ext_vector_type(4)));
typedef unsigned short u16;

#define MFMA16(a,b,c) __builtin_amdgcn_mfma_f32_16x16x32_f16((a),(b),(c),0,0,0)

__device__ __forceinline__ float b2f(u16 u) {
  unsigned v = ((unsigned)u) << 16;
  return __builtin_bit_cast(float, v);
}
__device__ __forceinline__ u16 f2b(float f) {  // RTN-even; inputs finite
  unsigned u = __builtin_bit_cast(unsigned, f);
  return (u16)((u + 0x7FFFu + ((u >> 16) & 1u)) >> 16);
}

// ---------------- dtype detector ----------------
// bf16 N(0,1) data: exponent field <= ~130. fp32 data read as shorts: half the
// shorts are low mantissa bits -> uniform "exponent" -> many hits > 141.
__global__ void detect_k(const void* x, int* flag) {
  __shared__ int cnt;
  if (threadIdx.x == 0) cnt = 0;
  __syncthreads();
  const u16* u = (const u16*)x;
  int c = 0;
  for (int i = threadIdx.x; i < 4096; i += 256) {
    int e = (u[i] >> 7) & 0xFF;
    if (e > 141) c++;
  }
  atomicAdd(&cnt, c);
  __syncthreads();
  if (threadIdx.x == 0) flag[0] = (cnt > 64) ? 0 : 1;  // 1 = bf16
}

// ---------------- maxpool 3x3 stride 2 ----------------
template<bool BF>
__device__ void maxpool_body(const void* x, float* xp) {
  int idx = blockIdx.x * 256 + threadIdx.x;
  if (idx >= TOT) return;
  int p  = idx % (HO * HO);
  int bc = idx / (HO * HO);
  int h = p / HO, w = p % HO;
  long base = ((long)bc * HIN + 2 * h) * HIN + 2 * w;
  float m = -3.0e38f;
#pragma unroll
  for (int dh = 0; dh < 3; dh++)
#pragma unroll
    for (int dw = 0; dw < 3; dw++) {
      long o = base + dh * HIN + dw;
      float v = BF ? b2f(((const u16*)x)[o]) : ((const float*)x)[o];
      m = fmaxf(m, v);
    }
  xp[idx] = m;
}
__global__ __launch_bounds__(256) void maxpool_k(const void* x, float* xp, const int* flag) {
  if (flag[0]) maxpool_body<true>(x, xp); else maxpool_body<false>(x, xp);
}

// ---------------- QKV 1x1 convs (fp32 vector GEMM) ----------------
// t=0: theta -> Qh/Ql (B,NPAD,D) fp16 hi/lo   (Q[n][c] = theta[c][n])
// t=1: phi   -> Kh/Kl (B,NPAD,D)
// t=2: g     -> Vt    (B,D,NPAD)  (natural layout = V^T)
template<bool BF>
__device__ void qkv_body(const float* __restrict__ xp, const void* tw, const void* pw, const void* gw,
                         _Float16* Qh, _Float16* Ql, _Float16* Kh, _Float16* Kl, _Float16* Vt) {
  int b = blockIdx.z;
  int t = blockIdx.y >> 3, ot = blockIdx.y & 7;   // 16 output channels per block
  int pb = blockIdx.x, tid = threadIdx.x;
  const void* w = (t == 0) ? tw : (t == 1) ? pw : gw;
  __shared__ float Wt[C_][16];                    // Wt[c][r] = W[ot*16+r][c]
#pragma unroll
  for (int i = 0; i < 16; i++) {
    int g = tid + i * 256;                        // 0..4095
    int r = g >> 8, c = g & 255;
    Wt[c][r] = BF ? b2f(((const u16*)w)[(ot * 16 + r) * C_ + c])
                  : ((const float*)w)[(ot * 16 + r) * C_ + c];
  }
  __syncthreads();
  int p0 = pb * 1024 + tid;
  const float* xb = xp + (long)b * C_ * NSEQ;
  bool val[4];
#pragma unroll
  for (int j = 0; j < 4; j++) val[j] = (p0 + j * 256) < NSEQ;
  float acc[16][4];
#pragma unroll
  for (int r = 0; r < 16; r++)
#pragma unroll
    for (int j = 0; j < 4; j++) acc[r][j] = 0.f;
  for (int c = 0; c < C_; c++) {
    float xv[4];
#pragma unroll
    for (int j = 0; j < 4; j++) xv[j] = val[j] ? xb[c * NSEQ + p0 + j * 256] : 0.f;
#pragma unroll
    for (int r4 = 0; r4 < 4; r4++) {
      f32x4 w4 = *(const f32x4*)&Wt[c][r4 * 4];
#pragma unroll
      for (int rr = 0; rr < 4; rr++)
#pragma unroll
        for (int j = 0; j < 4; j++) acc[r4 * 4 + rr][j] += w4[rr] * xv[j];
    }
  }
  long boff = (long)b * NPAD * D_;
  if (t < 2) {
    _Float16* dh = (t == 0 ? Qh : Kh) + boff;
    _Float16* dl = (t == 0 ? Ql : Kl) + boff;
#pragma unroll
    for (int j = 0; j < 4; j++) {
      if (!val[j]) continue;
      int p = p0 + j * 256;
      f16x8 hv[2], lv[2];
#pragma unroll
      for (int r = 0; r < 16; r++) {
        float a = acc[r][j];
        _Float16 h = (_Float16)a;
        float l = a - (float)h;
        hv[r >> 3][r & 7] = h;
        lv[r >> 3][r & 7] = (_Float16)l;
      }
      *(f16x8*)(dh + (long)p * D_ + ot * 16)     = hv[0];
      *(f16x8*)(dh + (long)p * D_ + ot * 16 + 8) = hv[1];
      *(f16x8*)(dl + (long)p * D_ + ot * 16)     = lv[0];
      *(f16x8*)(dl + (long)p * D_ + ot * 16 + 8) = lv[1];
    }
  } else {
    _Float16* dv = Vt + (long)b * D_ * NPAD;
#pragma unroll
    for (int r = 0; r < 16; r++)
#pragma unroll
      for (int j = 0; j < 4; j++) {
        int p = p0 + j * 256;
        if (val[j]) dv[(long)(ot * 16 + r) * NPAD + p] = (_Float16)acc[r][j];
      }
  }
}
__global__ __launch_bounds__(256) void qkv_k(const float* xp, const void* tw, const void* pw, const void* gw,
                                             _Float16* Qh, _Float16* Ql, _Float16* Kh, _Float16* Kl,
                                             _Float16* Vt, const int* flag) {
  if (flag[0]) qkv_body<true>(xp, tw, pw, gw, Qh, Ql, Kh, Kl, Vt);
  else         qkv_body<false>(xp, tw, pw, gw, Qh, Ql, Kh, Kl, Vt);
}

// ---------------- flash attention, fp16-split QK^T ----------------
// block = 4 waves, BM=64 Q rows (16/wave), BN=64 KV rows per iter.
// S = qh*kh + ql*kh + qh*kl + ql*kl  (4 MFMA passes -> ~fp32 logits)
__global__ __launch_bounds__(256) void flash_k(
    const _Float16* __restrict__ Qh, const _Float16* __restrict__ Ql,
    const _Float16* __restrict__ Kh, const _Float16* __restrict__ Kl,
    const _Float16* __restrict__ Vt, float* __restrict__ Y) {
  __shared__ _Float16 Ksh[64][136];    // K hi tile, padded stride (16B mult)
  __shared__ _Float16 Ksl[64][136];    // K lo tile
  __shared__ _Float16 Vs[128][72];     // V^T tile: [channel][m_local]
  __shared__ _Float16 Ps[4][16][72];   // per-wave P round-trip

  int b = blockIdx.y, qt = blockIdx.x;
  int tid = threadIdx.x, wave = tid >> 6, lane = tid & 63;
  int quad = lane >> 4, l16 = lane & 15;

  long boff = (long)b * NPAD * D_;
  const _Float16* Qhb = Qh + boff;
  const _Float16* Qlb = Ql + boff;
  const _Float16* Khb = Kh + boff;
  const _Float16* Klb = Kl + boff;
  const _Float16* Vb  = Vt + (long)b * D_ * NPAD;

  int qrow = qt * 64 + wave * 16 + l16;      // A-frag: m = lane&15
  f16x8 aqh[4], aql[4];
#pragma unroll
  for (int kk = 0; kk < 4; kk++) {
    aqh[kk] = *(const f16x8*)(Qhb + (long)qrow * D_ + kk * 32 + quad * 8);
    aql[kk] = *(const f16x8*)(Qlb + (long)qrow * D_ + kk * 32 + quad * 8);
  }

  f32x4 o_acc[8];
#pragma unroll
  for (int s = 0; s < 8; s++) o_acc[s] = (f32x4){0.f, 0.f, 0.f, 0.f};
  float m_r[4] = {-3e38f, -3e38f, -3e38f, -3e38f};
  float l_r[4] = {0.f, 0.f, 0.f, 0.f};
  const float LOG2E = 1.4426950408889634f;

  for (int t = 0; t < 63; t++) {
    __syncthreads();
#pragma unroll
    for (int i = 0; i < 4; i++) {       // stage K(hi,lo) + V tiles
      int ch = tid + i * 256;           // 0..1023
      int row = ch >> 4, col = (ch & 15) * 8;
      long go = (long)(t * 64 + row) * D_ + col;
      *(f16x8*)&Ksh[row][col] = *(const f16x8*)(Khb + go);
      *(f16x8*)&Ksl[row][col] = *(const f16x8*)(Klb + go);
      int c = ch >> 3, m8 = (ch & 7) * 8;
      *(f16x8*)&Vs[c][m8] = *(const f16x8*)(Vb + (long)c * NPAD + t * 64 + m8);
    }
    __syncthreads();

    f32x4 s_acc[4];
#pragma unroll
    for (int s = 0; s < 4; s++) s_acc[s] = (f32x4){0.f, 0.f, 0.f, 0.f};
#pragma unroll
    for (int s = 0; s < 4; s++) {
#pragma unroll
      for (int kk = 0; kk < 4; kk++) {
        f16x8 bh = *(const f16x8*)&Ksh[s * 16 + l16][kk * 32 + quad * 8];
        f16x8 bl = *(const f16x8*)&Ksl[s * 16 + l16][kk * 32 + quad * 8];
        s_acc[s] = MFMA16(aqh[kk], bh, s_acc[s]);
        s_acc[s] = MFMA16(aql[kk], bh, s_acc[s]);
        s_acc[s] = MFMA16(aqh[kk], bl, s_acc[s]);
        s_acc[s] = MFMA16(aql[kk], bl, s_acc[s]);
      }
    }
    // mask padded KV columns
#pragma unroll
    for (int s = 0; s < 4; s++) {
      if (t * 64 + s * 16 + l16 >= NSEQ) {
#pragma unroll
        for (int r = 0; r < 4; r++) s_acc[s][r] = -3e38f;
      }
    }
    // online softmax (rows = quad*4+r, cols across lanes&subtiles)
    float mx[4];
#pragma unroll
    for (int r = 0; r < 4; r++)
      mx[r] = fmaxf(fmaxf(s_acc[0][r], s_acc[1][r]), fmaxf(s_acc[2][r], s_acc[3][r]));
#pragma unroll
    for (int off = 1; off < 16; off <<= 1)
#pragma unroll
      for (int r = 0; r < 4; r++) mx[r] = fmaxf(mx[r], __shfl_xor(mx[r], off, 64));
    float alpha[4];
#pragma unroll
    for (int r = 0; r < 4; r++) {
      float mn = fmaxf(m_r[r], mx[r]);
      alpha[r] = exp2f((m_r[r] - mn) * LOG2E);
      m_r[r] = mn;
    }
    float pvv[4][4], rs[4] = {0.f, 0.f, 0.f, 0.f};
#pragma unroll
    for (int s = 0; s < 4; s++)
#pragma unroll
      for (int r = 0; r < 4; r++) {
        float p = exp2f((s_acc[s][r] - m_r[r]) * LOG2E);
        pvv[s][r] = p;
        rs[r] += p;
      }
#pragma unroll
    for (int off = 1; off < 16; off <<= 1)
#pragma unroll
      for (int r = 0; r < 4; r++) rs[r] += __shfl_xor(rs[r], off, 64);
#pragma unroll
    for (int r = 0; r < 4; r++) l_r[r] = l_r[r] * alpha[r] + rs[r];
#pragma unroll
    for (int s8 = 0; s8 < 8; s8++)
#pragma unroll
      for (int r = 0; r < 4; r++) o_acc[s8][r] *= alpha[r];
    // P: C-layout -> LDS -> A-layout
#pragma unroll
    for (int s = 0; s < 4; s++)
#pragma unroll
      for (int r = 0; r < 4; r++)
        Ps[wave][quad * 4 + r][s * 16 + l16] = (_Float16)pvv[s][r];
    __syncthreads();
    f16x8 ap[2];
#pragma unroll
    for (int kk2 = 0; kk2 < 2; kk2++)
      ap[kk2] = *(const f16x8*)&Ps[wave][l16][kk2 * 32 + quad * 8];
#pragma unroll
    for (int s8 = 0; s8 < 8; s8++)
#pragma unroll
      for (int kk2 = 0; kk2 < 2; kk2++) {
        f16x8 bv = *(const f16x8*)&Vs[s8 * 16 + l16][kk2 * 32 + quad * 8];
        o_acc[s8] = MFMA16(ap[kk2], bv, o_acc[s8]);
      }
  }
  float* Yb = Y + (long)b * NSEQ * D_;
#pragma unroll
  for (int r = 0; r < 4; r++) {
    int n = qt * 64 + wave * 16 + quad * 4 + r;
    if (n < NSEQ) {
      float inv = 1.0f / l_r[r];
#pragma unroll
      for (int s8 = 0; s8 < 8; s8++)
        Yb[(long)n * D_ + s8 * 16 + l16] = o_acc[s8][r] * inv;
    }
  }
}

// ---------------- y_w GEMM on raw-viewed y + BN partial stats ----------------
template<bool BF>
__device__ void out_body(const float* __restrict__ Y, const void* yw, float* outp,
                         float* gsum, float* gsumsq) {
  int b = blockIdx.z, ot = blockIdx.y, pb = blockIdx.x, tid = threadIdx.x;
  __shared__ float Wt[C2_][16];
  __shared__ float red[2][16][4];
#pragma unroll
  for (int i = 0; i < 8; i++) {
    int g = tid + i * 256;              // 0..2047
    int r = g >> 7, c = g & 127;
    Wt[c][r] = BF ? b2f(((const u16*)yw)[(ot * 16 + r) * C2_ + c])
                  : ((const float*)yw)[(ot * 16 + r) * C2_ + c];
  }
  __syncthreads();
  int p0 = pb * 1024 + tid;
  const float* Yb = Y + (long)b * NSEQ * D_;   // flat (C2, NSEQ) view
  bool val[4];
#pragma unroll
  for (int j = 0; j < 4; j++) val[j] = (p0 + j * 256) < NSEQ;
  float acc[16][4];
#pragma unroll
  for (int r = 0; r < 16; r++)
#pragma unroll
    for (int j = 0; j < 4; j++) acc[r][j] = 0.f;
  for (int c = 0; c < C2_; c++) {
    float xv[4];
#pragma unroll
    for (int j = 0; j < 4; j++) xv[j] = val[j] ? Yb[(long)c * NSEQ + p0 + j * 256] : 0.f;
#pragma unroll
    for (int r4 = 0; r4 < 4; r4++) {
      f32x4 w4 = *(const f32x4*)&Wt[c][r4 * 4];
#pragma unroll
      for (int rr = 0; rr < 4; rr++)
#pragma unroll
        for (int j = 0; j < 4; j++) acc[r4 * 4 + rr][j] += w4[rr] * xv[j];
    }
  }
  long ob = ((long)b * C_ + ot * 16) * NSEQ;
#pragma unroll
  for (int r = 0; r < 16; r++)
#pragma unroll
    for (int j = 0; j < 4; j++)
      if (val[j]) outp[ob + (long)r * NSEQ + p0 + j * 256] = acc[r][j];
  int wave = tid >> 6, lane = tid & 63;
#pragma unroll
  for (int r = 0; r < 16; r++) {
    float s = 0.f, q = 0.f;
#pragma unroll
    for (int j = 0; j < 4; j++) { s += acc[r][j]; q += acc[r][j] * acc[r][j]; }
#pragma unroll
    for (int off = 1; off < 64; off <<= 1) {
      s += __shfl_xor(s, off, 64);
      q += __shfl_xor(q, off, 64);
    }
    if (lane == 0) { red[0][r][wave] = s; red[1][r][wave] = q; }
  }
  __syncthreads();
  if (tid < 32) {
    int which = tid >> 4, r = tid & 15;
    float v = red[which][r][0] + red[which][r][1] + red[which][r][2] + red[which][r][3];
    atomicAdd((which ? gsumsq : gsum) + ot * 16 + r, v);
  }
}
__global__ __launch_bounds__(256) void out_k(const float* Y, const void* yw, float* outp,
                                             float* gsum, float* gsumsq, const int* flag) {
  if (flag[0]) out_body<true>(Y, yw, outp, gsum, gsumsq);
  else         out_body<false>(Y, yw, outp, gsum, gsumsq);
}

// ---------------- BN (training) + residual + relu ----------------
template<bool BF>
__device__ void bn_body(const float* outp, const float* gsum, const float* gsumsq,
                        const void* bnw, const void* bnb, const float* xp, void* out) {
  int idx = blockIdx.x * 256 + threadIdx.x;
  if (idx >= TOT) return;
  int c = (idx / NSEQ) & (C_ - 1);
  const float invn = 1.0f / (float)(B_ * NSEQ);
  float mean = gsum[c] * invn;
  float var = gsumsq[c] * invn - mean * mean;
  var = fmaxf(var, 0.f);
  float is = rsqrtf(var + 1e-5f);
  float w = BF ? b2f(((const u16*)bnw)[c]) : ((const float*)bnw)[c];
  float bb = BF ? b2f(((const u16*)bnb)[c]) : ((const float*)bnb)[c];
  float v = (outp[idx] - mean) * is * w + bb + xp[idx];
  v = fmaxf(v, 0.f);
  if (BF) ((u16*)out)[idx] = f2b(v);
  else    ((float*)out)[idx] = v;
}
__global__ __launch_bounds__(256) void bn_k(const float* outp, const float* gsum, const float* gsumsq,
                                            const void* bnw, const void* bnb, const float* xp,
                                            void* out, const int* flag) {
  if (flag[0]) bn_body<true>(outp, gsum, gsumsq, bnw, bnb, xp, out);
  else         bn_body<false>(outp, gsum, gsumsq, bnw, bnb, xp, out);
}

// ---------------- launcher ----------------
extern "C" void kernel_launch(void* const* d_in, const int* in_sizes, int n_in,
                              void* d_out, int out_size, void* d_ws, size_t ws_size,
                              hipStream_t stream) {
  size_t off = 0;
  auto alloc = [&](size_t bytes) -> char* {
    char* p = (char*)d_ws + off;
    off += (bytes + 255) & ~(size_t)255;
    return p;
  };
  float*    xp   = (float*)alloc(sizeof(float) * (size_t)TOT);
  _Float16* Qh   = (_Float16*)alloc(2 * (size_t)B_ * NPAD * D_);
  _Float16* Ql   = (_Float16*)alloc(2 * (size_t)B_ * NPAD * D_);
  _Float16* Kh   = (_Float16*)alloc(2 * (size_t)B_ * NPAD * D_);
  _Float16* Kl   = (_Float16*)alloc(2 * (size_t)B_ * NPAD * D_);
  _Float16* Vt   = (_Float16*)alloc(2 * (size_t)B_ * D_ * NPAD);
  float*    Yb   = (float*)alloc(sizeof(float) * (size_t)B_ * NSEQ * D_);
  float*    outp = (float*)alloc(sizeof(float) * (size_t)TOT);
  float*    gsum = (float*)alloc(1024);
  float*    gsq  = (float*)alloc(1024);
  int*      flag = (int*)alloc(256);

  hipMemsetAsync(gsum, 0, 1024, stream);
  hipMemsetAsync(gsq, 0, 1024, stream);

  detect_k<<<1, 256, 0, stream>>>(d_in[0], flag);
  maxpool_k<<<(TOT + 255) / 256, 256, 0, stream>>>(d_in[0], xp, flag);
  qkv_k<<<dim3(4, 24, B_), 256, 0, stream>>>(xp, d_in[1], d_in[2], d_in[3],
                                             Qh, Ql, Kh, Kl, Vt, flag);
  flash_k<<<dim3(63, B_), 256, 0, stream>>>(Qh, Ql, Kh, Kl, Vt, Yb);
  out_k<<<dim3(4, 16, B_), 256, 0, stream>>>(Yb, d_in[4], outp, gsum, gsq, flag);
  bn_k<<<(TOT + 255) / 256, 256, 0, stream>>>(outp, gsum, gsq, d_in[5], d_in[6], xp, d_out, flag);
}

// Round 2
// 418.607 us; speedup vs baseline: 1.1356x; 1.1356x over previous
//
#include <hip/hip_runtime.h>

#define B_   4
#define C_   256
#define C2_  128
#define HIN  128
#define HO   63
#define NSEQ 3969          // 63*63
#define NPAD 4032          // 63*64, keeps 16B row alignment
#define D_   128
#define TOT  (B_*C_*NSEQ)  // 4064256
#define SPLITS 3

typedef _Float16 f16x8 __attribute__((ext_vector_type(8)));
typedef short    s16x8 __attribute__((ext_vector_type(8)));
typedef float    f32x4 __attribute__((ext_vector_type(4)));
typedef unsigned short u16;
typedef u16 u16x8 __attribute__((ext_vector_type(8)));

#define MFMA16(a,b,c) __builtin_amdgcn_mfma_f32_16x16x32_f16((a),(b),(c),0,0,0)
#define MFMABF(a,b,c) __builtin_amdgcn_mfma_f32_16x16x32_bf16((a),(b),(c),0,0,0)

__device__ __forceinline__ float b2f(u16 u) {
  unsigned v = ((unsigned)u) << 16;
  return __builtin_bit_cast(float, v);
}
__device__ __forceinline__ u16 f2b(float f) {  // RTN-even; exact for bf16-exact values
  unsigned u = __builtin_bit_cast(unsigned, f);
  return (u16)((u + 0x7FFFu + ((u >> 16) & 1u)) >> 16);
}

// ---------------- dtype detector ----------------
__global__ void detect_k(const void* x, int* flag) {
  __shared__ int cnt;
  if (threadIdx.x == 0) cnt = 0;
  __syncthreads();
  const u16* u = (const u16*)x;
  int c = 0;
  for (int i = threadIdx.x; i < 4096; i += 256) {
    int e = (u[i] >> 7) & 0xFF;
    if (e > 141) c++;
  }
  atomicAdd(&cnt, c);
  __syncthreads();
  if (threadIdx.x == 0) flag[0] = (cnt > 64) ? 0 : 1;  // 1 = bf16
}

// ---------------- maxpool 3x3 stride 2 -> xp[bc][NPAD] (bf16 u16 or f32) ----------------
template<bool BF>
__device__ void maxpool_body(const void* x, void* xp) {
  int idx = blockIdx.x * 256 + threadIdx.x;
  if (idx >= TOT) return;
  int p  = idx % NSEQ;
  int bc = idx / NSEQ;
  int h = p / HO, w = p % HO;
  long base = ((long)bc * HIN + 2 * h) * HIN + 2 * w;
  float m = -3.0e38f;
#pragma unroll
  for (int dh = 0; dh < 3; dh++)
#pragma unroll
    for (int dw = 0; dw < 3; dw++) {
      long o = base + dh * HIN + dw;
      float v = BF ? b2f(((const u16*)x)[o]) : ((const float*)x)[o];
      m = fmaxf(m, v);
    }
  if (BF) ((u16*)xp)[(long)bc * NPAD + p] = f2b(m);   // exact (m is bf16-exact)
  else    ((float*)xp)[(long)bc * NPAD + p] = m;
}
__global__ __launch_bounds__(256) void maxpool_k(const void* x, void* xp, const int* flag) {
  if (flag[0]) maxpool_body<true>(x, xp); else maxpool_body<false>(x, xp);
}

// ---------------- xp (c,p) -> xpT (p,c), bf16, tiled via LDS ----------------
__global__ __launch_bounds__(256) void transpose_k(const u16* xp, u16* xpT, const int* flag) {
  if (!flag[0]) return;
  __shared__ unsigned T32[64][33];   // 2 p packed per dword; stride 33 -> <=2-way banks
  int pt = blockIdx.x, cg = blockIdx.y, b = blockIdx.z;
  int tid = threadIdx.x;
  const u16* src = xp + ((long)(b * C_ + cg * 64)) * NPAD + pt * 64;
#pragma unroll
  for (int i = 0; i < 2; i++) {
    int c = (tid >> 3) + i * 32, p8 = (tid & 7) * 8;
    u16x8 v = *(const u16x8*)(src + (long)c * NPAD + p8);
#pragma unroll
    for (int j = 0; j < 4; j++)
      T32[c][(p8 >> 1) + j] = (unsigned)v[2 * j] | ((unsigned)v[2 * j + 1] << 16);
  }
  __syncthreads();
  u16* dst = xpT + ((long)b * NPAD + pt * 64) * C_ + cg * 64;
#pragma unroll
  for (int i = 0; i < 2; i++) {
    int p = (tid >> 3) + i * 32, c8 = (tid & 7) * 8;
    if (pt * 64 + p >= NSEQ) continue;
    u16x8 v;
#pragma unroll
    for (int j = 0; j < 8; j++) {
      unsigned wrd = T32[c8 + j][p >> 1];
      v[j] = (u16)((p & 1) ? (wrd >> 16) : wrd);
    }
    *(u16x8*)(dst + (long)p * C_ + c8) = v;
  }
}

// ---------------- QKV via exact bf16 MFMA ----------------
// grid (63 p-tiles, 6 row-tiles of 64 over [theta|phi|g], B). Q/K layout:
// [b][cg=chan/16][NPAD p][16 chans] fp16 hi/lo. V: [b][chan][NPAD p] fp16.
__global__ __launch_bounds__(256) void qkv_mfma_k(
    const u16* __restrict__ xpT, const void* tw, const void* pw, const void* gw,
    u16* Qh, u16* Ql, u16* Kh, u16* Kl, _Float16* Vt, const int* flag) {
  if (!flag[0]) return;
  __shared__ u16 Asm[64][40];
  __shared__ u16 Bsm[64][40];
  __shared__ float Tsm[4][16][66];
  int pt = blockIdx.x, y = blockIdx.y, b = blockIdx.z;
  int tid = threadIdx.x, wave = tid >> 6, lane = tid & 63;
  int quad = lane >> 4, l16 = lane & 15;
  int mat = y >> 1;
  const u16* W  = (const u16*)((mat == 0) ? tw : (mat == 1) ? pw : gw);
  const u16* Wr = W + (long)((y & 1) * 64) * C_;
  const u16* Xb = xpT + ((long)b * NPAD + pt * 64) * C_;
  int sr = tid >> 2, su = (tid & 3) * 8;
  f32x4 acc[4];
#pragma unroll
  for (int s = 0; s < 4; s++) acc[s] = (f32x4){0.f, 0.f, 0.f, 0.f};
  for (int kc = 0; kc < C_; kc += 32) {
    __syncthreads();
    *(u16x8*)&Asm[sr][su] = *(const u16x8*)(Wr + (long)sr * C_ + kc + su);
    *(u16x8*)&Bsm[sr][su] = *(const u16x8*)(Xb + (long)sr * C_ + kc + su);
    __syncthreads();
    s16x8 a = *(const s16x8*)&Asm[wave * 16 + l16][quad * 8];
#pragma unroll
    for (int s = 0; s < 4; s++) {
      s16x8 bf = *(const s16x8*)&Bsm[s * 16 + l16][quad * 8];
      acc[s] = MFMABF(a, bf, acc[s]);
    }
  }
  int p0 = pt * 64;
  int chanb = (y & 1) * 64 + wave * 16;
  if (mat == 2) {
    _Float16* dv = Vt + (long)b * C2_ * NPAD;
#pragma unroll
    for (int s = 0; s < 4; s++)
#pragma unroll
      for (int r = 0; r < 4; r++) {
        int p = p0 + s * 16 + l16;
        if (p < NSEQ) dv[(long)(chanb + quad * 4 + r) * NPAD + p] = (_Float16)acc[s][r];
      }
  } else {
#pragma unroll
    for (int s = 0; s < 4; s++)
#pragma unroll
      for (int r = 0; r < 4; r++)
        Tsm[wave][quad * 4 + r][s * 16 + l16] = acc[s][r];
    int p = p0 + lane;                 // each lane owns one p, reads own wave's slice
    if (p < NSEQ) {
      u16* dh = (mat == 0 ? Qh : Kh) + (long)b * 8 * NPAD * 16;
      u16* dl = (mat == 0 ? Ql : Kl) + (long)b * 8 * NPAD * 16;
      int cgb = chanb >> 4;
      f16x8 hv[2], lv[2];
#pragma unroll
      for (int cl = 0; cl < 16; cl++) {
        float v = Tsm[wave][cl][lane];
        _Float16 h = (_Float16)v;
        float lo = v - (float)h;
        hv[cl >> 3][cl & 7] = h;
        lv[cl >> 3][cl & 7] = (_Float16)lo;
      }
      u16* ph = dh + ((long)cgb * NPAD + p) * 16;
      u16* pl = dl + ((long)cgb * NPAD + p) * 16;
      *(f16x8*)ph = hv[0]; *(f16x8*)(ph + 8) = hv[1];
      *(f16x8*)pl = lv[0]; *(f16x8*)(pl + 8) = lv[1];
    }
  }
}

// ---------------- QKV fp32 vector fallback (non-bf16 inputs) ----------------
__global__ __launch_bounds__(256) void qkv_vec_k(
    const float* __restrict__ xp, const void* tw, const void* pw, const void* gw,
    u16* Qh, u16* Ql, u16* Kh, u16* Kl, _Float16* Vt, const int* flag) {
  if (flag[0]) return;
  int b = blockIdx.z;
  int t = blockIdx.y >> 3, ot = blockIdx.y & 7;
  int pb = blockIdx.x, tid = threadIdx.x;
  const float* w = (const float*)((t == 0) ? tw : (t == 1) ? pw : gw);
  __shared__ float Wt[C_][16];
#pragma unroll
  for (int i = 0; i < 16; i++) {
    int g = tid + i * 256;
    int r = g >> 8, c = g & 255;
    Wt[c][r] = w[(ot * 16 + r) * C_ + c];
  }
  __syncthreads();
  int p0 = pb * 1024 + tid;
  const float* xb = xp + (long)b * C_ * NPAD;
  bool val[4];
#pragma unroll
  for (int j = 0; j < 4; j++) val[j] = (p0 + j * 256) < NSEQ;
  float acc[16][4];
#pragma unroll
  for (int r = 0; r < 16; r++)
#pragma unroll
    for (int j = 0; j < 4; j++) acc[r][j] = 0.f;
  for (int c = 0; c < C_; c++) {
    float xv[4];
#pragma unroll
    for (int j = 0; j < 4; j++) xv[j] = val[j] ? xb[(long)c * NPAD + p0 + j * 256] : 0.f;
#pragma unroll
    for (int r4 = 0; r4 < 4; r4++) {
      f32x4 w4 = *(const f32x4*)&Wt[c][r4 * 4];
#pragma unroll
      for (int rr = 0; rr < 4; rr++)
#pragma unroll
        for (int j = 0; j < 4; j++) acc[r4 * 4 + rr][j] += w4[rr] * xv[j];
    }
  }
  if (t < 2) {
    u16* dh = (t == 0 ? Qh : Kh) + (long)b * 8 * NPAD * 16;
    u16* dl = (t == 0 ? Ql : Kl) + (long)b * 8 * NPAD * 16;
#pragma unroll
    for (int j = 0; j < 4; j++) {
      if (!val[j]) continue;
      int p = p0 + j * 256;
      f16x8 hv[2], lv[2];
#pragma unroll
      for (int r = 0; r < 16; r++) {
        float a = acc[r][j];
        _Float16 h = (_Float16)a;
        float l = a - (float)h;
        hv[r >> 3][r & 7] = h;
        lv[r >> 3][r & 7] = (_Float16)l;
      }
      u16* ph = dh + ((long)ot * NPAD + p) * 16;
      u16* pl = dl + ((long)ot * NPAD + p) * 16;
      *(f16x8*)ph = hv[0]; *(f16x8*)(ph + 8) = hv[1];
      *(f16x8*)pl = lv[0]; *(f16x8*)(pl + 8) = lv[1];
    }
  } else {
    _Float16* dv = Vt + (long)b * C2_ * NPAD;
#pragma unroll
    for (int r = 0; r < 16; r++)
#pragma unroll
      for (int j = 0; j < 4; j++) {
        int p = p0 + j * 256;
        if (val[j]) dv[(long)(ot * 16 + r) * NPAD + p] = (_Float16)acc[r][j];
      }
  }
}

// ---------------- flash attention, KV-split, fp16-split QK^T (3 passes) ----------------
__global__ __launch_bounds__(256) void flash_k(
    const u16* __restrict__ Qh, const u16* __restrict__ Ql,
    const u16* __restrict__ Kh, const u16* __restrict__ Kl,
    const _Float16* __restrict__ Vt,
    float* __restrict__ Opart, float* __restrict__ Mp, float* __restrict__ Lp) {
  __shared__ __align__(16) char smem[53248];          // 52 KB -> 3 blocks/CU
  _Float16 (*Ksh)[136]    = (_Float16(*)[136])smem;          // 17408 B
  _Float16 (*Ksl)[136]    = (_Float16(*)[136])(smem + 17408);// 17408 B
  _Float16 (*Vs)[72]      = (_Float16(*)[72])(smem + 34816); // 18432 B
  _Float16 (*Ps)[16][72]  = (_Float16(*)[16][72])smem;       // aliases Ksh (9216 B)

  int qt = blockIdx.x, split = blockIdx.y, b = blockIdx.z;
  int tid = threadIdx.x, wave = tid >> 6, lane = tid & 63;
  int quad = lane >> 4, l16 = lane & 15;

  const u16* Qhb = Qh + (long)b * 8 * NPAD * 16;
  const u16* Qlb = Ql + (long)b * 8 * NPAD * 16;
  const u16* Khb = Kh + (long)b * 8 * NPAD * 16;
  const u16* Klb = Kl + (long)b * 8 * NPAD * 16;
  const _Float16* Vb = Vt + (long)b * C2_ * NPAD;

  int qrow = qt * 64 + wave * 16 + l16;
  f16x8 aqh[4], aql[4];
#pragma unroll
  for (int kk = 0; kk < 4; kk++) {
    int cg = kk * 2 + (quad >> 1), offc = (quad & 1) * 8;
    aqh[kk] = *(const f16x8*)(Qhb + ((long)cg * NPAD + qrow) * 16 + offc);
    aql[kk] = *(const f16x8*)(Qlb + ((long)cg * NPAD + qrow) * 16 + offc);
  }

  f32x4 o_acc[8];
#pragma unroll
  for (int s = 0; s < 8; s++) o_acc[s] = (f32x4){0.f, 0.f, 0.f, 0.f};
  float m_r[4] = {-3e38f, -3e38f, -3e38f, -3e38f};
  float l_r[4] = {0.f, 0.f, 0.f, 0.f};
  const float LOG2E = 1.4426950408889634f;

  int t0 = split * 21, t1 = t0 + 21;
  for (int t = t0; t < t1; t++) {
    __syncthreads();                     // (A) prior PV reads of Ps/Vs done
#pragma unroll
    for (int i = 0; i < 4; i++) {        // stage K(hi,lo) + V tiles
      int ch = tid + i * 256;            // 0..1023
      int row = ch >> 4, u = ch & 15;
      int cg = u >> 1, offc = (u & 1) * 8;
      long go = ((long)cg * NPAD + t * 64 + row) * 16 + offc;
      *(f16x8*)&Ksh[row][u * 8] = *(const f16x8*)(Khb + go);
      *(f16x8*)&Ksl[row][u * 8] = *(const f16x8*)(Klb + go);
      int c = ch >> 3, m8 = (ch & 7) * 8;
      *(f16x8*)&Vs[c][m8] = *(const f16x8*)(Vb + (long)c * NPAD + t * 64 + m8);
    }
    __syncthreads();                     // (B) tiles visible

    f32x4 s_acc[4];
#pragma unroll
    for (int s = 0; s < 4; s++) s_acc[s] = (f32x4){0.f, 0.f, 0.f, 0.f};
#pragma unroll
    for (int s = 0; s < 4; s++) {
#pragma unroll
      for (int kk = 0; kk < 4; kk++) {
        f16x8 bh = *(const f16x8*)&Ksh[s * 16 + l16][kk * 32 + quad * 8];
        f16x8 bl = *(const f16x8*)&Ksl[s * 16 + l16][kk * 32 + quad * 8];
        s_acc[s] = MFMA16(aqh[kk], bh, s_acc[s]);
        s_acc[s] = MFMA16(aql[kk], bh, s_acc[s]);
        s_acc[s] = MFMA16(aqh[kk], bl, s_acc[s]);   // ql*kl dropped (~2^-22)
      }
    }
#pragma unroll
    for (int s = 0; s < 4; s++) {
      if (t * 64 + s * 16 + l16 >= NSEQ) {
#pragma unroll
        for (int r = 0; r < 4; r++) s_acc[s][r] = -3e38f;
      }
    }
    float mx[4];
#pragma unroll
    for (int r = 0; r < 4; r++)
      mx[r] = fmaxf(fmaxf(s_acc[0][r], s_acc[1][r]), fmaxf(s_acc[2][r], s_acc[3][r]));
#pragma unroll
    for (int off = 1; off < 16; off <<= 1)
#pragma unroll
      for (int r = 0; r < 4; r++) mx[r] = fmaxf(mx[r], __shfl_xor(mx[r], off, 64));
    float alpha[4];
#pragma unroll
    for (int r = 0; r < 4; r++) {
      float mn = fmaxf(m_r[r], mx[r]);
      alpha[r] = exp2f((m_r[r] - mn) * LOG2E);
      m_r[r] = mn;
    }
    float pvv[4][4], rs[4] = {0.f, 0.f, 0.f, 0.f};
#pragma unroll
    for (int s = 0; s < 4; s++)
#pragma unroll
      for (int r = 0; r < 4; r++) {
        float p = exp2f((s_acc[s][r] - m_r[r]) * LOG2E);
        pvv[s][r] = p;
        rs[r] += p;
      }
#pragma unroll
    for (int off = 1; off < 16; off <<= 1)
#pragma unroll
      for (int r = 0; r < 4; r++) rs[r] += __shfl_xor(rs[r], off, 64);
#pragma unroll
    for (int r = 0; r < 4; r++) l_r[r] = l_r[r] * alpha[r] + rs[r];
#pragma unroll
    for (int s8 = 0; s8 < 8; s8++)
#pragma unroll
      for (int r = 0; r < 4; r++) o_acc[s8][r] *= alpha[r];
    __syncthreads();                     // (C) all waves done reading Ksh/Ksl
#pragma unroll
    for (int s = 0; s < 4; s++)
#pragma unroll
      for (int r = 0; r < 4; r++)
        Ps[wave][quad * 4 + r][s * 16 + l16] = (_Float16)pvv[s][r];
    __syncthreads();                     // (D) Ps visible
    f16x8 ap[2];
#pragma unroll
    for (int kk2 = 0; kk2 < 2; kk2++)
      ap[kk2] = *(const f16x8*)&Ps[wave][l16][kk2 * 32 + quad * 8];
#pragma unroll
    for (int s8 = 0; s8 < 8; s8++)
#pragma unroll
      for (int kk2 = 0; kk2 < 2; kk2++) {
        f16x8 bv = *(const f16x8*)&Vs[s8 * 16 + l16][kk2 * 32 + quad * 8];
        o_acc[s8] = MFMA16(ap[kk2], bv, o_acc[s8]);
      }
  }
  float* Ob = Opart + (long)(b * SPLITS + split) * NSEQ * D_;
  float* Mb = Mp + (long)(b * SPLITS + split) * NSEQ;
  float* Lb = Lp + (long)(b * SPLITS + split) * NSEQ;
#pragma unroll
  for (int r = 0; r < 4; r++) {
    int n = qt * 64 + wave * 16 + quad * 4 + r;
    if (n < NSEQ) {
#pragma unroll
      for (int s8 = 0; s8 < 8; s8++)
        Ob[(long)n * D_ + s8 * 16 + l16] = o_acc[s8][r];
      if (l16 == 0) { Mb[n] = m_r[r]; Lb[n] = l_r[r]; }
    }
  }
}

// ---------------- merge split partials ----------------
__global__ __launch_bounds__(256) void merge_k(const float* __restrict__ Opart,
                                               const float* __restrict__ Mp,
                                               const float* __restrict__ Lp,
                                               float* __restrict__ Y) {
  int row = blockIdx.x * 4 + (threadIdx.x >> 6);
  int lane = threadIdx.x & 63;
  int b = row / NSEQ, n = row - b * NSEQ;
  const float LOG2E = 1.4426950408889634f;
  float ms[SPLITS], m = -3e38f;
#pragma unroll
  for (int s = 0; s < SPLITS; s++) {
    ms[s] = Mp[(long)(b * SPLITS + s) * NSEQ + n];
    m = fmaxf(m, ms[s]);
  }
  float den = 0.f, a0 = 0.f, a1 = 0.f;
  int d = lane * 2;
#pragma unroll
  for (int s = 0; s < SPLITS; s++) {
    float w = exp2f((ms[s] - m) * LOG2E);
    den += Lp[(long)(b * SPLITS + s) * NSEQ + n] * w;
    const float* O = Opart + ((long)(b * SPLITS + s) * NSEQ + n) * D_ + d;
    a0 += w * O[0];
    a1 += w * O[1];
  }
  float inv = 1.f / den;
  float* Yo = Y + ((long)b * NSEQ + n) * D_ + d;
  Yo[0] = a0 * inv;
  Yo[1] = a1 * inv;
}

// ---------------- y_w GEMM on raw-viewed y + BN partial stats ----------------
template<bool BF>
__device__ void out_body(const float* __restrict__ Y, const void* yw, float* outp,
                         float* gsum, float* gsumsq) {
  int b = blockIdx.z, ot = blockIdx.y, pb = blockIdx.x, tid = threadIdx.x;
  __shared__ float Wt[C2_][16];
  __shared__ float red[2][16][4];
#pragma unroll
  for (int i = 0; i < 8; i++) {
    int g = tid + i * 256;
    int r = g >> 7, c = g & 127;
    Wt[c][r] = BF ? b2f(((const u16*)yw)[(ot * 16 + r) * C2_ + c])
                  : ((const float*)yw)[(ot * 16 + r) * C2_ + c];
  }
  __syncthreads();
  int p0 = pb * 1024 + tid;
  const float* Yb = Y + (long)b * NSEQ * D_;
  bool val[4];
#pragma unroll
  for (int j = 0; j < 4; j++) val[j] = (p0 + j * 256) < NSEQ;
  float acc[16][4];
#pragma unroll
  for (int r = 0; r < 16; r++)
#pragma unroll
    for (int j = 0; j < 4; j++) acc[r][j] = 0.f;
  for (int c = 0; c < C2_; c++) {
    float xv[4];
#pragma unroll
    for (int j = 0; j < 4; j++) xv[j] = val[j] ? Yb[(long)c * NSEQ + p0 + j * 256] : 0.f;
#pragma unroll
    for (int r4 = 0; r4 < 4; r4++) {
      f32x4 w4 = *(const f32x4*)&Wt[c][r4 * 4];
#pragma unroll
      for (int rr = 0; rr < 4; rr++)
#pragma unroll
        for (int j = 0; j < 4; j++) acc[r4 * 4 + rr][j] += w4[rr] * xv[j];
    }
  }
  long ob = ((long)b * C_ + ot * 16) * NSEQ;
#pragma unroll
  for (int r = 0; r < 16; r++)
#pragma unroll
    for (int j = 0; j < 4; j++)
      if (val[j]) outp[ob + (long)r * NSEQ + p0 + j * 256] = acc[r][j];
  int wave = tid >> 6, lane = tid & 63;
#pragma unroll
  for (int r = 0; r < 16; r++) {
    float s = 0.f, q = 0.f;
#pragma unroll
    for (int j = 0; j < 4; j++) { s += acc[r][j]; q += acc[r][j] * acc[r][j]; }
#pragma unroll
    for (int off = 1; off < 64; off <<= 1) {
      s += __shfl_xor(s, off, 64);
      q += __shfl_xor(q, off, 64);
    }
    if (lane == 0) { red[0][r][wave] = s; red[1][r][wave] = q; }
  }
  __syncthreads();
  if (tid < 32) {
    int which = tid >> 4, r = tid & 15;
    float v = red[which][r][0] + red[which][r][1] + red[which][r][2] + red[which][r][3];
    atomicAdd((which ? gsumsq : gsum) + ot * 16 + r, v);
  }
}
__global__ __launch_bounds__(256) void out_k(const float* Y, const void* yw, float* outp,
                                             float* gsum, float* gsumsq, const int* flag) {
  if (flag[0]) out_body<true>(Y, yw, outp, gsum, gsumsq);
  else         out_body<false>(Y, yw, outp, gsum, gsumsq);
}

// ---------------- BN (training) + residual + relu ----------------
template<bool BF>
__device__ void bn_body(const float* outp, const float* gsum, const float* gsumsq,
                        const void* bnw, const void* bnb, const void* xp, void* out) {
  int idx = blockIdx.x * 256 + threadIdx.x;
  if (idx >= TOT) return;
  int p = idx % NSEQ;
  int bc = idx / NSEQ;
  int c = bc & (C_ - 1);
  const float invn = 1.0f / (float)(B_ * NSEQ);
  float mean = gsum[c] * invn;
  float var = gsumsq[c] * invn - mean * mean;
  var = fmaxf(var, 0.f);
  float is = rsqrtf(var + 1e-5f);
  float w = BF ? b2f(((const u16*)bnw)[c]) : ((const float*)bnw)[c];
  float bb = BF ? b2f(((const u16*)bnb)[c]) : ((const float*)bnb)[c];
  float res = BF ? b2f(((const u16*)xp)[(long)bc * NPAD + p])
                 : ((const float*)xp)[(long)bc * NPAD + p];
  float v = (outp[idx] - mean) * is * w + bb + res;
  v = fmaxf(v, 0.f);
  if (BF) ((u16*)out)[idx] = f2b(v);
  else    ((float*)out)[idx] = v;
}
__global__ __launch_bounds__(256) void bn_k(const float* outp, const float* gsum, const float* gsumsq,
                                            const void* bnw, const void* bnb, const void* xp,
                                            void* out, const int* flag) {
  if (flag[0]) bn_body<true>(outp, gsum, gsumsq, bnw, bnb, xp, out);
  else         bn_body<false>(outp, gsum, gsumsq, bnw, bnb, xp, out);
}

// ---------------- launcher ----------------
extern "C" void kernel_launch(void* const* d_in, const int* in_sizes, int n_in,
                              void* d_out, int out_size, void* d_ws, size_t ws_size,
                              hipStream_t stream) {
  size_t off = 0;
  auto alloc = [&](size_t bytes) -> char* {
    char* p = (char*)d_ws + off;
    off += (bytes + 255) & ~(size_t)255;
    return p;
  };
  void*     xp   = alloc(sizeof(float) * (size_t)B_ * C_ * NPAD);      // 16.5 MB
  u16*      xpT  = (u16*)alloc(2 * (size_t)B_ * NPAD * C_);            // 8.3 MB
  u16*      Qh   = (u16*)alloc(2 * (size_t)B_ * 8 * NPAD * 16);        // 4.1 MB x4
  u16*      Ql   = (u16*)alloc(2 * (size_t)B_ * 8 * NPAD * 16);
  u16*      Kh   = (u16*)alloc(2 * (size_t)B_ * 8 * NPAD * 16);
  u16*      Kl   = (u16*)alloc(2 * (size_t)B_ * 8 * NPAD * 16);
  _Float16* Vt   = (_Float16*)alloc(2 * (size_t)B_ * C2_ * NPAD);      // 4.1 MB
  float*    Yb   = (float*)alloc(sizeof(float) * (size_t)B_ * NSEQ * D_); // 8.1 MB
  // big region: Opart (24.4 MB) during flash/merge, then outp (16.3 MB)
  float*    big  = (float*)alloc(sizeof(float) * (size_t)B_ * SPLITS * NSEQ * D_);
  float*    Mp   = (float*)alloc(sizeof(float) * (size_t)B_ * SPLITS * NSEQ);
  float*    Lp   = (float*)alloc(sizeof(float) * (size_t)B_ * SPLITS * NSEQ);
  float*    gsum = (float*)alloc(1024);
  float*    gsq  = (float*)alloc(1024);
  int*      flag = (int*)alloc(256);

  hipMemsetAsync(gsum, 0, 1024, stream);
  hipMemsetAsync(gsq, 0, 1024, stream);

  detect_k<<<1, 256, 0, stream>>>(d_in[0], flag);
  maxpool_k<<<(TOT + 255) / 256, 256, 0, stream>>>(d_in[0], xp, flag);
  transpose_k<<<dim3(63, 4, B_), 256, 0, stream>>>((const u16*)xp, xpT, flag);
  qkv_mfma_k<<<dim3(63, 6, B_), 256, 0, stream>>>(xpT, d_in[1], d_in[2], d_in[3],
                                                  Qh, Ql, Kh, Kl, Vt, flag);
  qkv_vec_k<<<dim3(4, 24, B_), 256, 0, stream>>>((const float*)xp, d_in[1], d_in[2], d_in[3],
                                                 Qh, Ql, Kh, Kl, Vt, flag);
  flash_k<<<dim3(63, SPLITS, B_), 256, 0, stream>>>(Qh, Ql, Kh, Kl, Vt, big, Mp, Lp);
  merge_k<<<3969, 256, 0, stream>>>(big, Mp, Lp, Yb);
  out_k<<<dim3(4, 16, B_), 256, 0, stream>>>(Yb, d_in[4], big, gsum, gsq, flag);
  bn_k<<<(TOT + 255) / 256, 256, 0, stream>>>(big, gsum, gsq, d_in[5], d_in[6], xp, d_out, flag);
}